// Round 16
// baseline (2386.353 us; speedup 1.0000x reference)
//
#include <hip/hip_runtime.h>
#include <math.h>

#define B_ 32
#define L_ 512
#define S_ 37
#define STATIC_ 8
#define D_ 768
#define DI_ 1536
#define N_ 16
#define DTR_ 48
#define NL_ 4
#define V_ 32
#define ROWS_ (B_*L_)      // 16384
#define KE_ 96             // padded embed K (74 -> 96)
#define TCH_ 64            // scan LDS chunk (timesteps)
#define NCHT_ (L_/TCH_)    // 8 chunks
#define TPW_ 66            // lsw2 row stride (f32x2)
#define TPO_ 68            // log row stride (u32)

typedef __bf16 bf16;
typedef __bf16 bf16x8 __attribute__((ext_vector_type(8)));
typedef __bf16 bf16x4 __attribute__((ext_vector_type(4)));
typedef __bf16 bf16x2 __attribute__((ext_vector_type(2)));
typedef float f32x4 __attribute__((ext_vector_type(4)));

typedef __attribute__((address_space(3))) void lds_void;
typedef __attribute__((address_space(1))) const void gmem_void;

__device__ __forceinline__ void gld16(const void* g, void* l) {
    __builtin_amdgcn_global_load_lds((gmem_void*)g, (lds_void*)l, 16, 0, 0);
}

__device__ __forceinline__ float silu_(float x) { return x / (1.f + __expf(-x)); }
__device__ __forceinline__ float softplus_(float x) {
    return fmaxf(x, 0.f) + __logf(1.f + __expf(-fabsf(x)));
}
__device__ __forceinline__ unsigned pack_bf2_(float a, float b) {
    bf16x2 v{(bf16)a, (bf16)b};
    return __builtin_bit_cast(unsigned, v);
}
template<int CTRL>
__device__ __forceinline__ float dpp_add_(float p) {
    int vi = __builtin_amdgcn_update_dpp(0, __builtin_bit_cast(int, p),
                                         CTRL, 0xF, 0xF, true);
    return p + __builtin_bit_cast(float, vi);
}

// ================= bf16 MFMA GEMM (legacy 128x128): C[M,*] = A[M,K] @ W[N,K]^T ==========
// MODE 0: f32 out (+addsrc), stride Nstore   [1-D grid, XCD swizzle; ntn = n-tiles]
// MODE 2: dt epilogue: swg[m*DI_+n] = pack(du,dtv)  [1-D grid, XCD swizzle]
// MODE 4: split-K partial (2-D grid); Nstore = CROWS (pbuf stride), ntn = K-slice len
template<int MODE>
__global__ __launch_bounds__(256) void gemm_mfma(
    const bf16* __restrict__ A, const bf16* __restrict__ W,
    const float* __restrict__ addsrc, void* __restrict__ Cv,
    int Nstore, int K, int ntn,
    const float* __restrict__ dt_bias, unsigned* __restrict__ swg,
    float* __restrict__ pbuf, const bf16* __restrict__ uref)
{
    __shared__ bf16 As[128 * 32];
    __shared__ bf16 Bs[128 * 32];
    const int tid = threadIdx.x;

    int m0, n0, kbeg, kend;
    if (MODE == 4) {
        m0 = blockIdx.y * 128; n0 = 0;
        kbeg = blockIdx.x * ntn; kend = kbeg + ntn;
    } else {
        int bid = blockIdx.x;
        int xcd = bid & 7, slot = bid >> 3;
        int Mtiles = gridDim.x / ntn;
        int mband = Mtiles >> 3;
        int m_tile = xcd * mband + slot / ntn;
        int n_tile = slot % ntn;
        m0 = m_tile * 128; n0 = n_tile * 128;
        kbeg = 0; kend = K;
    }

    f32x4 acc[4][4];
    #pragma unroll
    for (int i = 0; i < 4; i++)
        #pragma unroll
        for (int j = 0; j < 4; j++)
            acc[i][j] = f32x4{0.f, 0.f, 0.f, 0.f};

    const int srow = tid >> 2, spart = tid & 3;
    const bf16* ag = A + (size_t)(m0 + srow) * K + spart * 8;
    const bf16* wg = W + (size_t)(n0 + srow) * K + spart * 8;
    char* lA = (char*)As + tid * 16;
    char* lB = (char*)Bs + tid * 16;

    const int lane = tid & 63, wv = tid >> 6;
    const int wr = wv >> 1, wc = wv & 1;
    const int colL = lane & 15, quad = lane >> 4;
    const bf16* aRd = As + (wr * 64 + colL) * 32 + quad * 8;
    const bf16* bRd = Bs + (wc * 64 + colL) * 32 + quad * 8;

    for (int kt = kbeg; kt < kend; kt += 32) {
        gld16(ag + kt, lA);
        gld16(ag + kt + (size_t)64 * K, lA + 4096);
        gld16(wg + kt, lB);
        gld16(wg + kt + (size_t)64 * K, lB + 4096);
        __syncthreads();
        bf16x8 fa[4], fb[4];
        #pragma unroll
        for (int i = 0; i < 4; i++) fa[i] = *(const bf16x8*)(aRd + i * 16 * 32);
        #pragma unroll
        for (int j = 0; j < 4; j++) fb[j] = *(const bf16x8*)(bRd + j * 16 * 32);
        #pragma unroll
        for (int i = 0; i < 4; i++)
            #pragma unroll
            for (int j = 0; j < 4; j++)
                acc[i][j] = __builtin_amdgcn_mfma_f32_16x16x32_bf16(fa[i], fb[j], acc[i][j], 0, 0, 0);
        __syncthreads();
    }

    float* Cf = (float*)Cv;
    bf16*  Cb = (bf16*)Cv;
    #pragma unroll
    for (int i = 0; i < 4; i++) {
        #pragma unroll
        for (int j = 0; j < 4; j++) {
            int n = n0 + wc * 64 + j * 16 + colL;
            #pragma unroll
            for (int r = 0; r < 4; r++) {
                int m = m0 + wr * 64 + i * 16 + quad * 4 + r;
                float v = acc[i][j][r];
                if (MODE == 2) {
                    float dtv = softplus_(v + dt_bias[n]);
                    float u = (float)uref[(size_t)m * DI_ + n];
                    swg[(size_t)m * DI_ + n] = pack_bf2_(dtv * u, dtv);
                } else if (MODE == 4) {
                    if (n < 96)
                        pbuf[((size_t)blockIdx.x * Nstore + m) * 96 + n] = v;
                } else if (n < Nstore) {
                    if (addsrc) v += addsrc[(size_t)m * Nstore + n];
                    if (MODE == 1) Cb[(size_t)m * Nstore + n] = (bf16)v;
                    else           Cf[(size_t)m * Nstore + n] = v;
                }
            }
        }
    }
}

// ================= 256x256 8-phase bf16 GEMM (T2+T3+T4+T5) ==========================
template<int MODE>
__global__ __launch_bounds__(512, 2) void gemm256(
    const bf16* __restrict__ A, const bf16* __restrict__ W,
    const float* __restrict__ addsrc, void* __restrict__ Cv,
    int Nstore, int K, int ntn)
{
    __shared__ bf16 lds[65536];   // 131072 B
    const int tid = threadIdx.x;

    const int bid = blockIdx.x;
    const int qx = gridDim.x >> 3;
    const int wgid = (bid & 7) * qx + (bid >> 3);
    const int m0 = (wgid / ntn) * 256;
    const int n0 = (wgid % ntn) * 256;

    const int r0 = tid >> 3;                               // 0..63
    const int scol = ((tid & 7) * 8) ^ ((r0 & 7) << 3);    // elems
    const size_t sK = (size_t)K;
    const bf16* aSrc = A + (size_t)(m0 + r0) * sK + scol;
    const bf16* bSrc = W + (size_t)(n0 + r0) * sK + scol;
    char* ldst = (char*)lds + tid * 16;

#define STAGE_A(h, t) { const bf16* s_ = aSrc + (size_t)(h) * 128 * sK + (t) * 64;   \
    char* d_ = ldst + ((t) & 1) * 65536 + (h) * 16384;                               \
    gld16(s_, d_); gld16(s_ + 64 * sK, d_ + 8192); }
#define STAGE_B(h, t) { const bf16* s_ = bSrc + (size_t)(h) * 128 * sK + (t) * 64;   \
    char* d_ = ldst + ((t) & 1) * 65536 + 32768 + (h) * 16384;                       \
    gld16(s_, d_); gld16(s_ + 64 * sK, d_ + 8192); }

    const int lane = tid & 63, w = tid >> 6;
    const int wr = w >> 2, wc = w & 3;                     // 2M x 4N waves
    const int colL = lane & 15, quad = lane >> 4;
    const int sx = (colL & 7) << 3;
    const int c0 = (quad * 8) ^ sx;                        // kk=0 column (elems)
    const int c1 = c0 ^ 32;                               // kk=32 column
    const bf16* aRd0 = lds + wr * 8192 + colL * 64 + c0;
    const bf16* aRd1 = lds + wr * 8192 + colL * 64 + c1;
    const bf16* bRd0 = lds + 16384 + (wc >> 1) * 8192 + ((wc & 1) * 64 + colL) * 64 + c0;
    const bf16* bRd1 = lds + 16384 + (wc >> 1) * 8192 + ((wc & 1) * 64 + colL) * 64 + c1;

    f32x4 acc[8][4];
    #pragma unroll
    for (int i = 0; i < 8; i++)
        #pragma unroll
        for (int j = 0; j < 4; j++)
            acc[i][j] = f32x4{0.f, 0.f, 0.f, 0.f};
    bf16x8 aF[4][2], bF[4][2];

#define RD_A(buf, mp) { _Pragma("unroll") for (int i = 0; i < 4; i++) {              \
    aF[i][0] = *(const bf16x8*)(aRd0 + (buf) * 32768 + (mp) * 4096 + i * 1024);      \
    aF[i][1] = *(const bf16x8*)(aRd1 + (buf) * 32768 + (mp) * 4096 + i * 1024); } }
#define RD_B01(buf) { _Pragma("unroll") for (int j = 0; j < 2; j++) {                \
    bF[j][0] = *(const bf16x8*)(bRd0 + (buf) * 32768 + j * 1024);                    \
    bF[j][1] = *(const bf16x8*)(bRd1 + (buf) * 32768 + j * 1024); } }
#define RD_B23(buf) { _Pragma("unroll") for (int j = 0; j < 2; j++) {                \
    bF[2 + j][0] = *(const bf16x8*)(bRd0 + (buf) * 32768 + (2 + j) * 1024);          \
    bF[2 + j][1] = *(const bf16x8*)(bRd1 + (buf) * 32768 + (2 + j) * 1024); } }
#define MM(mp, np) { _Pragma("unroll") for (int i = 0; i < 4; i++)                   \
    _Pragma("unroll") for (int j = 0; j < 2; j++) {                                  \
    acc[(mp)*4+i][(np)*2+j] = __builtin_amdgcn_mfma_f32_16x16x32_bf16(               \
        aF[i][0], bF[(np)*2+j][0], acc[(mp)*4+i][(np)*2+j], 0, 0, 0);                \
    acc[(mp)*4+i][(np)*2+j] = __builtin_amdgcn_mfma_f32_16x16x32_bf16(               \
        aF[i][1], bF[(np)*2+j][1], acc[(mp)*4+i][(np)*2+j], 0, 0, 0); } }
#define MID_SYNC  __builtin_amdgcn_s_barrier();                                      \
    asm volatile("s_waitcnt lgkmcnt(0)" ::: "memory");                               \
    __builtin_amdgcn_sched_barrier(0);                                               \
    __builtin_amdgcn_s_setprio(1);
#define END_PHASE __builtin_amdgcn_s_setprio(0); __builtin_amdgcn_s_barrier();

    const int NT = K >> 6;
    const int NI = NT >> 1;

    STAGE_B(0, 0); STAGE_B(1, 0); STAGE_A(0, 0); STAGE_A(1, 0);
    STAGE_B(0, 1); STAGE_B(1, 1);
    asm volatile("s_waitcnt vmcnt(4)" ::: "memory");
    __builtin_amdgcn_s_barrier();

    for (int it = 0; it < NI; ++it) {
        const int t0 = 2 * it, t1 = t0 + 1;
        const bool nlast = (it + 1 < NI);
        RD_A(0, 0); RD_B01(0);
        STAGE_A(0, t1);
        MID_SYNC; MM(0, 0); END_PHASE;
        RD_B23(0);
        STAGE_A(1, t1);
        MID_SYNC; MM(0, 1); END_PHASE;
        RD_A(0, 1);
        if (nlast) STAGE_B(0, t0 + 2);
        MID_SYNC; MM(1, 0); END_PHASE;
        if (nlast) STAGE_B(1, t0 + 2);
        MID_SYNC; MM(1, 1);
        __builtin_amdgcn_s_setprio(0);
        if (nlast) { asm volatile("s_waitcnt vmcnt(4)" ::: "memory"); }
        else       { asm volatile("s_waitcnt vmcnt(0)" ::: "memory"); }
        __builtin_amdgcn_s_barrier();
        RD_A(1, 0); RD_B01(1);
        if (nlast) STAGE_A(0, t0 + 2);
        MID_SYNC; MM(0, 0); END_PHASE;
        RD_B23(1);
        if (nlast) STAGE_A(1, t0 + 2);
        MID_SYNC; MM(0, 1); END_PHASE;
        RD_A(1, 1);
        if (nlast) STAGE_B(0, t1 + 2);
        MID_SYNC; MM(1, 0); END_PHASE;
        if (nlast) STAGE_B(1, t1 + 2);
        MID_SYNC; MM(1, 1);
        __builtin_amdgcn_s_setprio(0);
        if (nlast) { asm volatile("s_waitcnt vmcnt(4)" ::: "memory"); }
        __builtin_amdgcn_s_barrier();
    }

    float* Cf = (float*)Cv;
    bf16*  Cb = (bf16*)Cv;
    #pragma unroll
    for (int f = 0; f < 8; f++) {
        #pragma unroll
        for (int j = 0; j < 4; j++) {
            int n = n0 + wc * 64 + j * 16 + colL;
            #pragma unroll
            for (int r = 0; r < 4; r++) {
                int m = m0 + wr * 128 + f * 16 + quad * 4 + r;
                float v = acc[f][j][r];
                if (MODE == 0) {
                    v += addsrc[(size_t)m * Nstore + n];
                    Cf[(size_t)m * Nstore + n] = v;
                } else {
                    Cb[(size_t)m * Nstore + n] = (bf16)v;
                }
            }
        }
    }
#undef STAGE_A
#undef STAGE_B
#undef RD_A
#undef RD_B01
#undef RD_B23
#undef MM
#undef MID_SYNC
#undef END_PHASE
}

// reduce split-K partials (runtime ks) -> dtr (bf16) + bcf (f32 pairs (B,C), swizzled
// per-(b,chunk) 8KB blocks: base (bb*8+ct)*8192, byte (n*512 + tl*8 + hi*4) ^ ((n&7)<<4))
__global__ __launch_bounds__(256) void xpost_kernel(const float* __restrict__ pbuf,
                                                    bf16* __restrict__ dtr,
                                                    float* __restrict__ bcf,
                                                    int crows, int ks) {
    int idx = blockIdx.x * 256 + threadIdx.x;   // crows*96
    int m = idx / 96, j = idx % 96;
    float s = pbuf[idx];
    for (int k = 1; k < ks; k++) s += pbuf[(size_t)k * crows * 96 + idx];
    if (j < 64) {
        dtr[(size_t)m * 64 + j] = (bf16)s;
    } else {
        int jj = j - 64;
        int n = jj & 15, hi = jj >> 4;    // hi=0 -> B, hi=1 -> C
        int bb = m >> 9, t = m & 511;
        int ct = t >> 6, tl = t & 63;
        int byo = (n * 512 + tl * 8 + hi * 4) ^ ((n & 7) << 4);
        *(float*)((char*)bcf + (size_t)(bb * 8 + ct) * 8192 + byo) = s;
    }
}

// ================= small prep kernels =================
__global__ __launch_bounds__(256) void cast2_f2b_kernel(const float* __restrict__ s1,
                                                        bf16* __restrict__ d1,
                                                        const float* __restrict__ s2,
                                                        bf16* __restrict__ d2,
                                                        unsigned n1) {
    size_t i = (size_t)blockIdx.x * 256 + threadIdx.x;
    if (i < n1) d1[i] = (bf16)s1[i];
    else        d2[i - n1] = (bf16)s2[i - n1];
}

__global__ __launch_bounds__(256) void pad_lm_kernel(const float* __restrict__ s, bf16* __restrict__ d) {
    int i = blockIdx.x * 256 + threadIdx.x;     // 128*768
    int row = i / D_;
    d[i] = (row < V_) ? (bf16)s[i] : (bf16)0.f;
}

__global__ __launch_bounds__(256) void pad_embw_kernel(const float* __restrict__ s, bf16* __restrict__ d) {
    int i = blockIdx.x * 256 + threadIdx.x;     // 768*96
    int row = i / KE_, col = i % KE_;
    d[i] = (col < 2 * S_) ? (bf16)s[row * 2 * S_ + col] : (bf16)0.f;
}

__global__ __launch_bounds__(256) void feats_kernel(const float* __restrict__ x,
                                                    const int* __restrict__ mask,
                                                    bf16* __restrict__ d) {
    size_t i = (size_t)blockIdx.x * 256 + threadIdx.x;  // ROWS_*96
    size_t row = i / KE_;
    int col = (int)(i % KE_);
    float v = 0.f;
    if (col < S_) v = x[row * S_ + col];
    else if (col < 2 * S_) v = (float)mask[row * S_ + (col - S_)];
    d[i] = (bf16)v;
}

// x_proj padded+remapped: (NL,128,1536) rows: 0..47=dt_r, 48..63=0, 64..95=B|C, 96..127=0
__global__ __launch_bounds__(256) void xpw_pad_kernel(const float* __restrict__ xpw,
                                                      bf16* __restrict__ d) {
    int l = blockIdx.y;
    int idx = blockIdx.x * 256 + threadIdx.x;   // 128*1536
    int row = idx / DI_, col = idx % DI_;
    float v = 0.f;
    if (row < DTR_) v = xpw[((size_t)l * (DTR_ + 2 * N_) + row) * DI_ + col];
    else if (row >= 64 && row < 96) v = xpw[((size_t)l * (DTR_ + 2 * N_) + row - 16) * DI_ + col];
    d[(size_t)l * 128 * DI_ + idx] = (bf16)v;
}

// dt_proj_w padded: (NL,1536,64), cols 48..63 = 0
__global__ __launch_bounds__(256) void dtw_pad_kernel(const float* __restrict__ dtw,
                                                      bf16* __restrict__ d) {
    int l = blockIdx.y;
    int idx = blockIdx.x * 256 + threadIdx.x;   // 1536*64
    int row = idx / 64, c = idx % 64;
    float v = (c < DTR_) ? dtw[((size_t)l * DI_ + row) * DTR_ + c] : 0.f;
    d[(size_t)l * DI_ * 64 + idx] = (bf16)v;
}

__global__ __launch_bounds__(256) void sstat_kernel(const float* __restrict__ stat,
                                                    const float* __restrict__ static_w,
                                                    const float* __restrict__ static_b,
                                                    const float* __restrict__ emb_b,
                                                    float* __restrict__ sstat) {
    int i = blockIdx.x * 256 + threadIdx.x;  // B_*D_
    int d = i % D_, b = i / D_;
    float acc = emb_b[d] + static_b[d];
    const float* sw = static_w + (size_t)d * STATIC_;
    const float* sv = stat + (size_t)b * STATIC_;
    #pragma unroll
    for (int s = 0; s < STATIC_; s++) acc += sv[s] * sw[s];
    sstat[i] = acc;
}

__device__ __forceinline__ void block_reduce2_(float& a, float& b, float* sbuf) {
    #pragma unroll
    for (int off = 32; off > 0; off >>= 1) {
        a += __shfl_down(a, off, 64);
        b += __shfl_down(b, off, 64);
    }
    int lane = threadIdx.x & 63, wid = threadIdx.x >> 6;
    if (lane == 0) { sbuf[wid] = a; sbuf[4 + wid] = b; }
    __syncthreads();
    a = sbuf[0] + sbuf[1] + sbuf[2] + sbuf[3];
    b = sbuf[4] + sbuf[5] + sbuf[6] + sbuf[7];
}

__global__ __launch_bounds__(256) void ln_embed_kernel(const float* __restrict__ h_pre,
                                                       const float* __restrict__ sstat,
                                                       const float* __restrict__ ln_w,
                                                       const float* __restrict__ ln_b,
                                                       float* __restrict__ h) {
    int row = blockIdx.x, b = row / L_, tid = threadIdx.x;
    __shared__ float sbuf[8];
    float v[3], sum = 0.f, sq = 0.f;
    #pragma unroll
    for (int j = 0; j < 3; j++) {
        int d = tid + 256 * j;
        v[j] = h_pre[(size_t)row * D_ + d] + sstat[b * D_ + d];
        sum += v[j]; sq += v[j] * v[j];
    }
    block_reduce2_(sum, sq, sbuf);
    float mu = sum * (1.f / D_);
    float rstd = rsqrtf(sq * (1.f / D_) - mu * mu + 1e-5f);
    #pragma unroll
    for (int j = 0; j < 3; j++) {
        int d = tid + 256 * j;
        h[(size_t)row * D_ + d] = (v[j] - mu) * rstd * ln_w[d] + ln_b[d];
    }
}

__global__ __launch_bounds__(256) void rmsnorm_bf_kernel(const float* __restrict__ h,
                                                         const float* __restrict__ w,
                                                         bf16* __restrict__ out) {
    int row = blockIdx.x, tid = threadIdx.x;
    __shared__ float sbuf[8];
    float v[3], ss = 0.f, dummy = 0.f;
    #pragma unroll
    for (int j = 0; j < 3; j++) {
        v[j] = h[(size_t)row * D_ + tid + 256 * j];
        ss += v[j] * v[j];
    }
    block_reduce2_(ss, dummy, sbuf);
    float rstd = rsqrtf(ss * (1.f / D_) + 1e-5f);
    #pragma unroll
    for (int j = 0; j < 3; j++) {
        int d = tid + 256 * j;
        out[(size_t)row * D_ + d] = (bf16)(v[j] * rstd * w[d]);
    }
}

// conv K=4 + silu -> xc (4 channels/thread) ; gate u32 per (row,d) -> gag
__global__ __launch_bounds__(256) void conv_silu_kernel(const bf16* __restrict__ xzb,
                                                        const float* __restrict__ cw,
                                                        const float* __restrict__ cb,
                                                        const float* __restrict__ Dp,
                                                        bf16* __restrict__ xcb,
                                                        unsigned* __restrict__ gag) {
    size_t idx = (size_t)blockIdx.x * 256 + threadIdx.x;   // crows*DI_/4
    int d4 = (int)(idx % (DI_ / 4));
    size_t row = idx / (DI_ / 4);
    int t = (int)(row % L_);
    int d = d4 * 4;
    const uint2* xz64 = (const uint2*)xzb;                 // row stride 768 uint2
    size_t base = row * 768 + d4;
    uint2 z2{0u, 0u};
    uint2 p0  = xz64[base];
    uint2 pm1 = (t >= 1) ? xz64[base - 768]     : z2;
    uint2 pm2 = (t >= 2) ? xz64[base - 2 * 768] : z2;
    uint2 pm3 = (t >= 3) ? xz64[base - 3 * 768] : z2;
    uint2 pz  = xz64[base + 384];

    bf16x4 a0 = __builtin_bit_cast(bf16x4, p0);
    bf16x4 a1 = __builtin_bit_cast(bf16x4, pm1);
    bf16x4 a2 = __builtin_bit_cast(bf16x4, pm2);
    bf16x4 a3 = __builtin_bit_cast(bf16x4, pm3);
    bf16x4 az = __builtin_bit_cast(bf16x4, pz);

    float cbl[4], Dl[4];
    *(float4*)cbl = ((const float4*)cb)[d4];
    *(float4*)Dl  = ((const float4*)Dp)[d4];

    float u[4];
    unsigned gv[4];
    #pragma unroll
    for (int c = 0; c < 4; c++) {
        float4 wc = ((const float4*)cw)[d + c];
        float acc = cbl[c] + wc.x * (float)a3[c] + wc.y * (float)a2[c]
                           + wc.z * (float)a1[c] + wc.w * (float)a0[c];
        u[c] = silu_(acc);
        float gz = silu_((float)az[c]);
        gv[c] = pack_bf2_(Dl[c] * u[c] * gz, gz);
    }
    ((uint2*)xcb)[row * (DI_ / 4) + d4] = uint2{pack_bf2_(u[0], u[1]), pack_bf2_(u[2], u[3])};
    *(uint4*)(gag + row * DI_ + d) = uint4{gv[0], gv[1], gv[2], gv[3]};
}

// ============== single-pass scan v2.1: single-buffered lsw2/logds (occupancy) ==============
__global__ __launch_bounds__(256) void scan_lds_kernel(const float* __restrict__ bcf,
                                                       const unsigned* __restrict__ swg,
                                                       const unsigned* __restrict__ gag,
                                                       const float* __restrict__ A_log,
                                                       bf16* __restrict__ yb) {
    __shared__ float2   lsw2[16][TPW_];
    __shared__ char     lbcf[2][8192];
    __shared__ unsigned logds[16][TPO_];
    const int tid = threadIdx.x;
    const int n = tid & 15, dl = tid >> 4;
    const int d0 = blockIdx.x * 16;
    const int d = d0 + dl;
    const int b = blockIdx.y;
    const float AvL = -__expf(A_log[(size_t)d * N_ + n]) * 1.44269504f;
    const size_t seqbase = (size_t)b * L_;

    const char* bcf_base = (const char*)bcf + (size_t)b * NCHT_ * 8192;
    unsigned swr[4], gar[4];

    #define BCF_GLD(c) { const char* s_ = bcf_base + (size_t)(c) * 8192 + tid * 16;  \
        char* d_ = (char*)lbcf + ((c) & 1) * 8192 + tid * 16;                        \
        gld16(s_, d_); gld16(s_ + 4096, d_ + 4096); }
    #define REG_LOAD(c) { size_t rb = seqbase + (size_t)(c) * TCH_;                  \
        _Pragma("unroll") for (int i = 0; i < 4; i++) {                              \
            size_t g = (rb + dl + 16 * i) * DI_ + d0 + n;                            \
            swr[i] = swg[g]; gar[i] = gag[g]; } }
    #define DSWRITE() { _Pragma("unroll") for (int i = 0; i < 4; i++) {              \
            int t = dl + 16 * i;                                                     \
            bf16x2 w2 = __builtin_bit_cast(bf16x2, swr[i]);                          \
            lsw2[n][t] = float2{(float)w2.x, (float)w2.y};                           \
            logds[n][t] = gar[i]; } }

    BCF_GLD(0);
    REG_LOAD(0);
    DSWRITE();
    __syncthreads();
    REG_LOAD(1);

    float h = 0.f;
    for (int c = 0; c < NCHT_; c++) {
        if (c + 1 < NCHT_) BCF_GLD(c + 1);
        bf16* pyc = yb + (seqbase + (size_t)c * TCH_) * DI_ + d;
        const char* bcrow = (const char*)lbcf + (c & 1) * 8192;
        #pragma unroll
        for (int tb = 0; tb < TCH_; tb += 16) {
            float res = 0.f;
            #pragma unroll
            for (int tq = 0; tq < 16; tq += 2) {
                float4 dd = *(const float4*)&lsw2[dl][tb + tq];
                int byo = (n * 512 + (tb + tq) * 8) ^ ((n & 7) << 4);
                float4 bc = *(const float4*)(bcrow + byo);
                #pragma unroll
                for (int u = 0; u < 2; u++) {
                    float du  = u ? dd.z : dd.x;
                    float dtv = u ? dd.w : dd.y;
                    float Bv  = u ? bc.z : bc.x;
                    float Cv  = u ? bc.w : bc.y;
                    float dA = __builtin_amdgcn_exp2f(dtv * AvL);
                    h = dA * h + du * Bv;
                    float pq = h * Cv;
                    pq = dpp_add_<0xB1>(pq);
                    pq = dpp_add_<0x4E>(pq);
                    pq = dpp_add_<0x124>(pq);
                    pq = dpp_add_<0x128>(pq);
                    if (n == tq + u) res = pq;   // loop-invariant cmp -> hoisted mask
                }
            }
            unsigned og = logds[dl][tb + n];
            bf16x2 o2 = __builtin_bit_cast(bf16x2, og);
            pyc[(size_t)(tb + n) * DI_] = (bf16)(res * (float)o2.y + (float)o2.x);
        }
        if (c + 1 < NCHT_) {
            __syncthreads();             // all reads of chunk c done
            DSWRITE();                   // overwrite single-buffer streams with c+1
            __syncthreads();             // writes visible (also drains BCF_GLD vmcnt)
            if (c + 2 < NCHT_) REG_LOAD(c + 2);
        }
    }
    #undef BCF_GLD
    #undef REG_LOAD
    #undef DSWRITE
}

extern "C" void kernel_launch(void* const* d_in, const int* in_sizes, int n_in,
                              void* d_out, int out_size, void* d_ws, size_t ws_size,
                              hipStream_t stream) {
    const float* x        = (const float*)d_in[0];
    const float* stat     = (const float*)d_in[1];
    const int*   mask     = (const int*)d_in[3];
    const float* emb_w    = (const float*)d_in[5];
    const float* emb_b    = (const float*)d_in[6];
    const float* static_w = (const float*)d_in[7];
    const float* static_b = (const float*)d_in[8];
    const float* ln_w     = (const float*)d_in[9];
    const float* ln_b     = (const float*)d_in[10];
    const float* norm_w   = (const float*)d_in[11];
    const float* in_proj_w  = (const float*)d_in[12];
    const float* conv_w   = (const float*)d_in[13];
    const float* conv_b   = (const float*)d_in[14];
    const float* x_proj_w = (const float*)d_in[15];
    const float* dt_proj_w= (const float*)d_in[16];
    const float* dt_proj_b= (const float*)d_in[17];
    const float* A_log    = (const float*)d_in[18];
    const float* D_param  = (const float*)d_in[19];
    const float* out_proj_w = (const float*)d_in[20];
    const float* norm_f_w = (const float*)d_in[21];
    const float* lm_head_w= (const float*)d_in[22];
    float* out = (float*)d_out;

    // ---- batch chunking (CB=8; ws < 318 MiB rules out larger tiers -- measured R4/R6) ----
    const int CBr = 8;
    const int CROWSr = CBr * L_;
    const int NCHr = B_ / CBr;

    // tiers (cumulative): deepks@224MiB (+6.3e6) -> precast@246MiB (+21.2e6)
    //                     -> pairproj@268MiB (+31.5e6; max need 274.4e6 <= 281.0e6)
    const bool deepks   = (ws_size >= (size_t)224 * 1024 * 1024);
    const bool precast  = (ws_size >= (size_t)246 * 1024 * 1024);
    const bool pairproj = (ws_size >= (size_t)268 * 1024 * 1024);
    const int KSr  = deepks ? 8 : 4;
    const int KSLr = DI_ / KSr;
    const int NLW  = precast ? NL_ : 1;
    const int PAIRr = pairproj ? 2 : 1;

    // ---- workspace layout (bytes) ----
    char* p = (char*)d_ws;
    float*    h      = (float*)p;         p += (size_t)ROWS_ * D_ * 4;           // 50.3 MB
    bf16*     hn_bf  = (bf16*)p;          p += (size_t)PAIRr * CROWSr * D_ * 2;
    char*     xz_region = p;                                                     // h_pre alias start
    bf16*     xz_bf  = (bf16*)p;          p += (size_t)PAIRr * CROWSr * 2 * DI_ * 2;
    bf16*     xc_bf  = (bf16*)p;          p += (size_t)CROWSr * DI_ * 2;
    unsigned* sw_g   = (unsigned*)p;      p += (size_t)CROWSr * DI_ * 4;
    unsigned* gate_g = (unsigned*)p;      p += (size_t)CROWSr * DI_ * 4;
    float*    bcf    = (float*)p;         p += (size_t)CROWSr * 32 * 4;
    bf16*     dtr_bf = (bf16*)p;          p += (size_t)CROWSr * 64 * 2;
    float*    pbuf   = (float*)p;         p += (size_t)KSr * CROWSr * 96 * 4;
    bf16*     y_bf   = (bf16*)p;          p += (size_t)ROWS_ * DI_ * 2;          // 50.3 (FULL batch)
    bf16*     inw_w  = (bf16*)p;          p += (size_t)NLW * 2 * DI_ * D_ * 2;
    bf16*     outw_w = (bf16*)p;          p += (size_t)NLW * D_ * DI_ * 2;
    bf16*     xpwp_bf= (bf16*)p;          p += (size_t)NL_ * 128 * DI_ * 2;      // 1.6
    bf16*     dtwp_bf= (bf16*)p;          p += (size_t)NL_ * DI_ * 64 * 2;       // 0.8
    bf16*     lmw_bf = (bf16*)p;          p += (size_t)128 * D_ * 2;
    bf16*     embw_bf= (bf16*)p;          p += (size_t)D_ * KE_ * 2;
    bf16*     feats  = (bf16*)p;          p += (size_t)ROWS_ * KE_ * 2;          // 3.1
    float*    sstat  = (float*)p;         p += (size_t)B_ * D_ * 4;
    float*    h_pre  = (float*)xz_region; // 50.3 MB alias over xz/xc/sw_g (dead then)
    bf16*     hn_full= (bf16*)sw_g;       // 25.2 MB alias (sw_g dead at final stage)

    // ---- weight prep ----
    pad_lm_kernel<<<(128 * D_) / 256, 256, 0, stream>>>(lm_head_w, lmw_bf);
    pad_embw_kernel<<<(D_ * KE_) / 256, 256, 0, stream>>>(emb_w, embw_bf);
    feats_kernel<<<(ROWS_ * KE_) / 256, 256, 0, stream>>>(x, mask, feats);
    dim3 gxp((128 * DI_) / 256, NL_);
    xpw_pad_kernel<<<gxp, 256, 0, stream>>>(x_proj_w, xpwp_bf);
    dim3 gdt((DI_ * 64) / 256, NL_);
    dtw_pad_kernel<<<gdt, 256, 0, stream>>>(dt_proj_w, dtwp_bf);
    sstat_kernel<<<(B_ * D_) / 256, 256, 0, stream>>>(stat, static_w, static_b, emb_b, sstat);
    if (precast) {
        const unsigned nin = (unsigned)(NL_ * 2 * DI_ * D_);
        const unsigned ntot = nin + (unsigned)(NL_ * D_ * DI_);
        cast2_f2b_kernel<<<ntot / 256, 256, 0, stream>>>(
            in_proj_w, inw_w, out_proj_w, outw_w, nin);
    }

    // ---- embed + LN ----
    gemm_mfma<0><<<(D_ / 128) * (ROWS_ / 128), 256, 0, stream>>>(
        feats, embw_bf, nullptr, h_pre, D_, KE_, D_ / 128,
        nullptr, nullptr, nullptr, nullptr);
    ln_embed_kernel<<<ROWS_, 256, 0, stream>>>(h_pre, sstat, ln_w, ln_b, h);

    // ---- layers ----
    for (int l = 0; l < NL_; l++) {
        const bf16* inw_l;
        const bf16* outw_l;
        if (precast) {
            inw_l  = inw_w  + (size_t)l * 2 * DI_ * D_;
            outw_l = outw_w + (size_t)l * D_ * DI_;
        } else {
            const unsigned nin = (unsigned)(2 * DI_ * D_);
            const unsigned ntot = nin + (unsigned)(D_ * DI_);
            cast2_f2b_kernel<<<ntot / 256, 256, 0, stream>>>(
                in_proj_w + (size_t)l * 2 * DI_ * D_, inw_w,
                out_proj_w + (size_t)l * D_ * DI_, outw_w, nin);
            inw_l = inw_w; outw_l = outw_w;
        }

        for (int cp = 0; cp < NCHr / PAIRr; cp++) {
            const int cbase = cp * PAIRr;
            float* hc = h + (size_t)cbase * CROWSr * D_;

            // rmsnorm + in_proj over PAIRr chunks in one launch each
            rmsnorm_bf_kernel<<<PAIRr * CROWSr, 256, 0, stream>>>(
                hc, norm_w + (size_t)l * D_, hn_bf);

            // 256x256 8-phase GEMM: M=PAIRr*CROWSr, N=3072, K=768
            gemm256<1><<<(PAIRr * CROWSr / 256) * (2 * DI_ / 256), 512, 0, stream>>>(
                hn_bf, inw_l, nullptr, xz_bf, 2 * DI_, D_, 2 * DI_ / 256);

            for (int hh = 0; hh < PAIRr; hh++) {
                const int c = cbase + hh;
                const bf16* xzh = xz_bf + (size_t)hh * CROWSr * 2 * DI_;

                conv_silu_kernel<<<(CROWSr * (DI_ / 4)) / 256, 256, 0, stream>>>(
                    xzh, conv_w + (size_t)l * DI_ * 4, conv_b + (size_t)l * DI_,
                    D_param + (size_t)l * DI_, xc_bf, gate_g);

                dim3 g2a(KSr, CROWSr / 128);
                gemm_mfma<4><<<g2a, 256, 0, stream>>>(
                    xc_bf, xpwp_bf + (size_t)l * 128 * DI_,
                    nullptr, nullptr, CROWSr, DI_, KSLr,
                    nullptr, nullptr, pbuf, nullptr);
                xpost_kernel<<<(CROWSr * 96) / 256, 256, 0, stream>>>(
                    pbuf, dtr_bf, bcf, CROWSr, KSr);

                gemm_mfma<2><<<(DI_ / 128) * (CROWSr / 128), 256, 0, stream>>>(
                    dtr_bf, dtwp_bf + (size_t)l * DI_ * 64, nullptr, nullptr, 0, 64,
                    DI_ / 128, dt_proj_b + (size_t)l * DI_, sw_g, nullptr, xc_bf);

                dim3 gs(DI_ / 16, CBr);
                scan_lds_kernel<<<gs, 256, 0, stream>>>(bcf, sw_g, gate_g,
                                                        A_log + (size_t)l * DI_ * N_,
                                                        y_bf + (size_t)c * CROWSr * DI_);
            }
        }

        // 256x256 8-phase GEMM: M=16384, N=768, K=1536 -> 192 blocks, residual add
        gemm256<0><<<(ROWS_ / 256) * (D_ / 256), 512, 0, stream>>>(
            y_bf, outw_l, h, h, D_, DI_, D_ / 256);
    }

    // ---- final rmsnorm + lm_head (full batch) ----
    rmsnorm_bf_kernel<<<ROWS_, 256, 0, stream>>>(h, norm_f_w, hn_full);
    gemm_mfma<0><<<ROWS_ / 128, 256, 0, stream>>>(
        hn_full, lmw_bf, nullptr, out, V_, D_, 1,
        nullptr, nullptr, nullptr, nullptr);
}

// Round 17
// 2375.739 us; speedup vs baseline: 1.0045x; 1.0045x over previous
//
#include <hip/hip_runtime.h>
#include <math.h>

#define B_ 32
#define L_ 512
#define S_ 37
#define STATIC_ 8
#define D_ 768
#define DI_ 1536
#define N_ 16
#define DTR_ 48
#define NL_ 4
#define V_ 32
#define ROWS_ (B_*L_)      // 16384
#define KE_ 96             // padded embed K (74 -> 96)
#define TCH_ 64            // scan LDS chunk (timesteps)
#define NCHT_ (L_/TCH_)    // 8 chunks
#define TPW_ 66            // lsw2 row stride (f32x2)
#define TPO_ 68            // log row stride (u32)

typedef __bf16 bf16;
typedef __bf16 bf16x8 __attribute__((ext_vector_type(8)));
typedef __bf16 bf16x4 __attribute__((ext_vector_type(4)));
typedef __bf16 bf16x2 __attribute__((ext_vector_type(2)));
typedef float f32x4 __attribute__((ext_vector_type(4)));

typedef __attribute__((address_space(3))) void lds_void;
typedef __attribute__((address_space(1))) const void gmem_void;

__device__ __forceinline__ void gld16(const void* g, void* l) {
    __builtin_amdgcn_global_load_lds((gmem_void*)g, (lds_void*)l, 16, 0, 0);
}

__device__ __forceinline__ float silu_(float x) { return x / (1.f + __expf(-x)); }
__device__ __forceinline__ float softplus_(float x) {
    return fmaxf(x, 0.f) + __logf(1.f + __expf(-fabsf(x)));
}
__device__ __forceinline__ unsigned pack_bf2_(float a, float b) {
    bf16x2 v{(bf16)a, (bf16)b};
    return __builtin_bit_cast(unsigned, v);
}
template<int CTRL>
__device__ __forceinline__ float dpp_add_(float p) {
    int vi = __builtin_amdgcn_update_dpp(0, __builtin_bit_cast(int, p),
                                         CTRL, 0xF, 0xF, true);
    return p + __builtin_bit_cast(float, vi);
}

// ================= bf16 MFMA GEMM (legacy 128x128): C[M,*] = A[M,K] @ W[N,K]^T ==========
// MODE 0: f32 out (+addsrc), stride Nstore   [1-D grid, XCD swizzle; ntn = n-tiles]
// MODE 2: dt epilogue: swg[m*DI_+n] = pack(du,dtv)  [1-D grid, XCD swizzle]
// MODE 4: split-K partial (2-D grid); Nstore = CROWS (pbuf stride), ntn = K-slice len
template<int MODE>
__global__ __launch_bounds__(256) void gemm_mfma(
    const bf16* __restrict__ A, const bf16* __restrict__ W,
    const float* __restrict__ addsrc, void* __restrict__ Cv,
    int Nstore, int K, int ntn,
    const float* __restrict__ dt_bias, unsigned* __restrict__ swg,
    float* __restrict__ pbuf, const bf16* __restrict__ uref)
{
    __shared__ bf16 As[128 * 32];
    __shared__ bf16 Bs[128 * 32];
    const int tid = threadIdx.x;

    int m0, n0, kbeg, kend;
    if (MODE == 4) {
        m0 = blockIdx.y * 128; n0 = 0;
        kbeg = blockIdx.x * ntn; kend = kbeg + ntn;
    } else {
        int bid = blockIdx.x;
        int xcd = bid & 7, slot = bid >> 3;
        int Mtiles = gridDim.x / ntn;
        int mband = Mtiles >> 3;
        int m_tile = xcd * mband + slot / ntn;
        int n_tile = slot % ntn;
        m0 = m_tile * 128; n0 = n_tile * 128;
        kbeg = 0; kend = K;
    }

    f32x4 acc[4][4];
    #pragma unroll
    for (int i = 0; i < 4; i++)
        #pragma unroll
        for (int j = 0; j < 4; j++)
            acc[i][j] = f32x4{0.f, 0.f, 0.f, 0.f};

    const int srow = tid >> 2, spart = tid & 3;
    const bf16* ag = A + (size_t)(m0 + srow) * K + spart * 8;
    const bf16* wg = W + (size_t)(n0 + srow) * K + spart * 8;
    char* lA = (char*)As + tid * 16;
    char* lB = (char*)Bs + tid * 16;

    const int lane = tid & 63, wv = tid >> 6;
    const int wr = wv >> 1, wc = wv & 1;
    const int colL = lane & 15, quad = lane >> 4;
    const bf16* aRd = As + (wr * 64 + colL) * 32 + quad * 8;
    const bf16* bRd = Bs + (wc * 64 + colL) * 32 + quad * 8;

    for (int kt = kbeg; kt < kend; kt += 32) {
        gld16(ag + kt, lA);
        gld16(ag + kt + (size_t)64 * K, lA + 4096);
        gld16(wg + kt, lB);
        gld16(wg + kt + (size_t)64 * K, lB + 4096);
        __syncthreads();
        bf16x8 fa[4], fb[4];
        #pragma unroll
        for (int i = 0; i < 4; i++) fa[i] = *(const bf16x8*)(aRd + i * 16 * 32);
        #pragma unroll
        for (int j = 0; j < 4; j++) fb[j] = *(const bf16x8*)(bRd + j * 16 * 32);
        #pragma unroll
        for (int i = 0; i < 4; i++)
            #pragma unroll
            for (int j = 0; j < 4; j++)
                acc[i][j] = __builtin_amdgcn_mfma_f32_16x16x32_bf16(fa[i], fb[j], acc[i][j], 0, 0, 0);
        __syncthreads();
    }

    float* Cf = (float*)Cv;
    bf16*  Cb = (bf16*)Cv;
    #pragma unroll
    for (int i = 0; i < 4; i++) {
        #pragma unroll
        for (int j = 0; j < 4; j++) {
            int n = n0 + wc * 64 + j * 16 + colL;
            #pragma unroll
            for (int r = 0; r < 4; r++) {
                int m = m0 + wr * 64 + i * 16 + quad * 4 + r;
                float v = acc[i][j][r];
                if (MODE == 2) {
                    float dtv = softplus_(v + dt_bias[n]);
                    float u = (float)uref[(size_t)m * DI_ + n];
                    swg[(size_t)m * DI_ + n] = pack_bf2_(dtv * u, dtv);
                } else if (MODE == 4) {
                    if (n < 96)
                        pbuf[((size_t)blockIdx.x * Nstore + m) * 96 + n] = v;
                } else if (n < Nstore) {
                    if (addsrc) v += addsrc[(size_t)m * Nstore + n];
                    if (MODE == 1) Cb[(size_t)m * Nstore + n] = (bf16)v;
                    else           Cf[(size_t)m * Nstore + n] = v;
                }
            }
        }
    }
}

// ================= 256x256 8-phase bf16 GEMM (T2+T3+T4+T5) ==========================
template<int MODE>
__global__ __launch_bounds__(512, 2) void gemm256(
    const bf16* __restrict__ A, const bf16* __restrict__ W,
    const float* __restrict__ addsrc, void* __restrict__ Cv,
    int Nstore, int K, int ntn)
{
    __shared__ bf16 lds[65536];   // 131072 B
    const int tid = threadIdx.x;

    const int bid = blockIdx.x;
    const int qx = gridDim.x >> 3;
    const int wgid = (bid & 7) * qx + (bid >> 3);
    const int m0 = (wgid / ntn) * 256;
    const int n0 = (wgid % ntn) * 256;

    const int r0 = tid >> 3;                               // 0..63
    const int scol = ((tid & 7) * 8) ^ ((r0 & 7) << 3);    // elems
    const size_t sK = (size_t)K;
    const bf16* aSrc = A + (size_t)(m0 + r0) * sK + scol;
    const bf16* bSrc = W + (size_t)(n0 + r0) * sK + scol;
    char* ldst = (char*)lds + tid * 16;

#define STAGE_A(h, t) { const bf16* s_ = aSrc + (size_t)(h) * 128 * sK + (t) * 64;   \
    char* d_ = ldst + ((t) & 1) * 65536 + (h) * 16384;                               \
    gld16(s_, d_); gld16(s_ + 64 * sK, d_ + 8192); }
#define STAGE_B(h, t) { const bf16* s_ = bSrc + (size_t)(h) * 128 * sK + (t) * 64;   \
    char* d_ = ldst + ((t) & 1) * 65536 + 32768 + (h) * 16384;                       \
    gld16(s_, d_); gld16(s_ + 64 * sK, d_ + 8192); }

    const int lane = tid & 63, w = tid >> 6;
    const int wr = w >> 2, wc = w & 3;                     // 2M x 4N waves
    const int colL = lane & 15, quad = lane >> 4;
    const int sx = (colL & 7) << 3;
    const int c0 = (quad * 8) ^ sx;                        // kk=0 column (elems)
    const int c1 = c0 ^ 32;                               // kk=32 column
    const bf16* aRd0 = lds + wr * 8192 + colL * 64 + c0;
    const bf16* aRd1 = lds + wr * 8192 + colL * 64 + c1;
    const bf16* bRd0 = lds + 16384 + (wc >> 1) * 8192 + ((wc & 1) * 64 + colL) * 64 + c0;
    const bf16* bRd1 = lds + 16384 + (wc >> 1) * 8192 + ((wc & 1) * 64 + colL) * 64 + c1;

    f32x4 acc[8][4];
    #pragma unroll
    for (int i = 0; i < 8; i++)
        #pragma unroll
        for (int j = 0; j < 4; j++)
            acc[i][j] = f32x4{0.f, 0.f, 0.f, 0.f};
    bf16x8 aF[4][2], bF[4][2];

#define RD_A(buf, mp) { _Pragma("unroll") for (int i = 0; i < 4; i++) {              \
    aF[i][0] = *(const bf16x8*)(aRd0 + (buf) * 32768 + (mp) * 4096 + i * 1024);      \
    aF[i][1] = *(const bf16x8*)(aRd1 + (buf) * 32768 + (mp) * 4096 + i * 1024); } }
#define RD_B01(buf) { _Pragma("unroll") for (int j = 0; j < 2; j++) {                \
    bF[j][0] = *(const bf16x8*)(bRd0 + (buf) * 32768 + j * 1024);                    \
    bF[j][1] = *(const bf16x8*)(bRd1 + (buf) * 32768 + j * 1024); } }
#define RD_B23(buf) { _Pragma("unroll") for (int j = 0; j < 2; j++) {                \
    bF[2 + j][0] = *(const bf16x8*)(bRd0 + (buf) * 32768 + (2 + j) * 1024);          \
    bF[2 + j][1] = *(const bf16x8*)(bRd1 + (buf) * 32768 + (2 + j) * 1024); } }
#define MM(mp, np) { _Pragma("unroll") for (int i = 0; i < 4; i++)                   \
    _Pragma("unroll") for (int j = 0; j < 2; j++) {                                  \
    acc[(mp)*4+i][(np)*2+j] = __builtin_amdgcn_mfma_f32_16x16x32_bf16(               \
        aF[i][0], bF[(np)*2+j][0], acc[(mp)*4+i][(np)*2+j], 0, 0, 0);                \
    acc[(mp)*4+i][(np)*2+j] = __builtin_amdgcn_mfma_f32_16x16x32_bf16(               \
        aF[i][1], bF[(np)*2+j][1], acc[(mp)*4+i][(np)*2+j], 0, 0, 0); } }
#define MID_SYNC  __builtin_amdgcn_s_barrier();                                      \
    asm volatile("s_waitcnt lgkmcnt(0)" ::: "memory");                               \
    __builtin_amdgcn_sched_barrier(0);                                               \
    __builtin_amdgcn_s_setprio(1);
#define END_PHASE __builtin_amdgcn_s_setprio(0); __builtin_amdgcn_s_barrier();

    const int NT = K >> 6;
    const int NI = NT >> 1;

    STAGE_B(0, 0); STAGE_B(1, 0); STAGE_A(0, 0); STAGE_A(1, 0);
    STAGE_B(0, 1); STAGE_B(1, 1);
    asm volatile("s_waitcnt vmcnt(4)" ::: "memory");
    __builtin_amdgcn_s_barrier();

    for (int it = 0; it < NI; ++it) {
        const int t0 = 2 * it, t1 = t0 + 1;
        const bool nlast = (it + 1 < NI);
        RD_A(0, 0); RD_B01(0);
        STAGE_A(0, t1);
        MID_SYNC; MM(0, 0); END_PHASE;
        RD_B23(0);
        STAGE_A(1, t1);
        MID_SYNC; MM(0, 1); END_PHASE;
        RD_A(0, 1);
        if (nlast) STAGE_B(0, t0 + 2);
        MID_SYNC; MM(1, 0); END_PHASE;
        if (nlast) STAGE_B(1, t0 + 2);
        MID_SYNC; MM(1, 1);
        __builtin_amdgcn_s_setprio(0);
        if (nlast) { asm volatile("s_waitcnt vmcnt(4)" ::: "memory"); }
        else       { asm volatile("s_waitcnt vmcnt(0)" ::: "memory"); }
        __builtin_amdgcn_s_barrier();
        RD_A(1, 0); RD_B01(1);
        if (nlast) STAGE_A(0, t0 + 2);
        MID_SYNC; MM(0, 0); END_PHASE;
        RD_B23(1);
        if (nlast) STAGE_A(1, t0 + 2);
        MID_SYNC; MM(0, 1); END_PHASE;
        RD_A(1, 1);
        if (nlast) STAGE_B(0, t1 + 2);
        MID_SYNC; MM(1, 0); END_PHASE;
        if (nlast) STAGE_B(1, t1 + 2);
        MID_SYNC; MM(1, 1);
        __builtin_amdgcn_s_setprio(0);
        if (nlast) { asm volatile("s_waitcnt vmcnt(4)" ::: "memory"); }
        __builtin_amdgcn_s_barrier();
    }

    float* Cf = (float*)Cv;
    bf16*  Cb = (bf16*)Cv;
    #pragma unroll
    for (int f = 0; f < 8; f++) {
        #pragma unroll
        for (int j = 0; j < 4; j++) {
            int n = n0 + wc * 64 + j * 16 + colL;
            #pragma unroll
            for (int r = 0; r < 4; r++) {
                int m = m0 + wr * 128 + f * 16 + quad * 4 + r;
                float v = acc[f][j][r];
                if (MODE == 0) {
                    v += addsrc[(size_t)m * Nstore + n];
                    Cf[(size_t)m * Nstore + n] = v;
                } else {
                    Cb[(size_t)m * Nstore + n] = (bf16)v;
                }
            }
        }
    }
#undef STAGE_A
#undef STAGE_B
#undef RD_A
#undef RD_B01
#undef RD_B23
#undef MM
#undef MID_SYNC
#undef END_PHASE
}

// reduce split-K partials (runtime ks) -> dtr (bf16) + bcf (f32 pairs (B,C), swizzled
// per-(b,chunk) 8KB blocks: base (bb*8+ct)*8192, byte (n*512 + tl*8 + hi*4) ^ ((n&7)<<4))
__global__ __launch_bounds__(256) void xpost_kernel(const float* __restrict__ pbuf,
                                                    bf16* __restrict__ dtr,
                                                    float* __restrict__ bcf,
                                                    int crows, int ks) {
    int idx = blockIdx.x * 256 + threadIdx.x;   // crows*96
    int m = idx / 96, j = idx % 96;
    float s = pbuf[idx];
    for (int k = 1; k < ks; k++) s += pbuf[(size_t)k * crows * 96 + idx];
    if (j < 64) {
        dtr[(size_t)m * 64 + j] = (bf16)s;
    } else {
        int jj = j - 64;
        int n = jj & 15, hi = jj >> 4;    // hi=0 -> B, hi=1 -> C
        int bb = m >> 9, t = m & 511;
        int ct = t >> 6, tl = t & 63;
        int byo = (n * 512 + tl * 8 + hi * 4) ^ ((n & 7) << 4);
        *(float*)((char*)bcf + (size_t)(bb * 8 + ct) * 8192 + byo) = s;
    }
}

// ================= small prep kernels =================
__global__ __launch_bounds__(256) void cast2_f2b_kernel(const float* __restrict__ s1,
                                                        bf16* __restrict__ d1,
                                                        const float* __restrict__ s2,
                                                        bf16* __restrict__ d2,
                                                        unsigned n1) {
    size_t i = (size_t)blockIdx.x * 256 + threadIdx.x;
    if (i < n1) d1[i] = (bf16)s1[i];
    else        d2[i - n1] = (bf16)s2[i - n1];
}

__global__ __launch_bounds__(256) void pad_lm_kernel(const float* __restrict__ s, bf16* __restrict__ d) {
    int i = blockIdx.x * 256 + threadIdx.x;     // 128*768
    int row = i / D_;
    d[i] = (row < V_) ? (bf16)s[i] : (bf16)0.f;
}

__global__ __launch_bounds__(256) void pad_embw_kernel(const float* __restrict__ s, bf16* __restrict__ d) {
    int i = blockIdx.x * 256 + threadIdx.x;     // 768*96
    int row = i / KE_, col = i % KE_;
    d[i] = (col < 2 * S_) ? (bf16)s[row * 2 * S_ + col] : (bf16)0.f;
}

__global__ __launch_bounds__(256) void feats_kernel(const float* __restrict__ x,
                                                    const int* __restrict__ mask,
                                                    bf16* __restrict__ d) {
    size_t i = (size_t)blockIdx.x * 256 + threadIdx.x;  // ROWS_*96
    size_t row = i / KE_;
    int col = (int)(i % KE_);
    float v = 0.f;
    if (col < S_) v = x[row * S_ + col];
    else if (col < 2 * S_) v = (float)mask[row * S_ + (col - S_)];
    d[i] = (bf16)v;
}

// x_proj padded+remapped: (NL,128,1536) rows: 0..47=dt_r, 48..63=0, 64..95=B|C, 96..127=0
__global__ __launch_bounds__(256) void xpw_pad_kernel(const float* __restrict__ xpw,
                                                      bf16* __restrict__ d) {
    int l = blockIdx.y;
    int idx = blockIdx.x * 256 + threadIdx.x;   // 128*1536
    int row = idx / DI_, col = idx % DI_;
    float v = 0.f;
    if (row < DTR_) v = xpw[((size_t)l * (DTR_ + 2 * N_) + row) * DI_ + col];
    else if (row >= 64 && row < 96) v = xpw[((size_t)l * (DTR_ + 2 * N_) + row - 16) * DI_ + col];
    d[(size_t)l * 128 * DI_ + idx] = (bf16)v;
}

// dt_proj_w padded: (NL,1536,64), cols 48..63 = 0
__global__ __launch_bounds__(256) void dtw_pad_kernel(const float* __restrict__ dtw,
                                                      bf16* __restrict__ d) {
    int l = blockIdx.y;
    int idx = blockIdx.x * 256 + threadIdx.x;   // 1536*64
    int row = idx / 64, c = idx % 64;
    float v = (c < DTR_) ? dtw[((size_t)l * DI_ + row) * DTR_ + c] : 0.f;
    d[(size_t)l * DI_ * 64 + idx] = (bf16)v;
}

__global__ __launch_bounds__(256) void sstat_kernel(const float* __restrict__ stat,
                                                    const float* __restrict__ static_w,
                                                    const float* __restrict__ static_b,
                                                    const float* __restrict__ emb_b,
                                                    float* __restrict__ sstat) {
    int i = blockIdx.x * 256 + threadIdx.x;  // B_*D_
    int d = i % D_, b = i / D_;
    float acc = emb_b[d] + static_b[d];
    const float* sw = static_w + (size_t)d * STATIC_;
    const float* sv = stat + (size_t)b * STATIC_;
    #pragma unroll
    for (int s = 0; s < STATIC_; s++) acc += sv[s] * sw[s];
    sstat[i] = acc;
}

__device__ __forceinline__ void block_reduce2_(float& a, float& b, float* sbuf) {
    #pragma unroll
    for (int off = 32; off > 0; off >>= 1) {
        a += __shfl_down(a, off, 64);
        b += __shfl_down(b, off, 64);
    }
    int lane = threadIdx.x & 63, wid = threadIdx.x >> 6;
    if (lane == 0) { sbuf[wid] = a; sbuf[4 + wid] = b; }
    __syncthreads();
    a = sbuf[0] + sbuf[1] + sbuf[2] + sbuf[3];
    b = sbuf[4] + sbuf[5] + sbuf[6] + sbuf[7];
}

__global__ __launch_bounds__(256) void ln_embed_kernel(const float* __restrict__ h_pre,
                                                       const float* __restrict__ sstat,
                                                       const float* __restrict__ ln_w,
                                                       const float* __restrict__ ln_b,
                                                       float* __restrict__ h) {
    int row = blockIdx.x, b = row / L_, tid = threadIdx.x;
    __shared__ float sbuf[8];
    float v[3], sum = 0.f, sq = 0.f;
    #pragma unroll
    for (int j = 0; j < 3; j++) {
        int d = tid + 256 * j;
        v[j] = h_pre[(size_t)row * D_ + d] + sstat[b * D_ + d];
        sum += v[j]; sq += v[j] * v[j];
    }
    block_reduce2_(sum, sq, sbuf);
    float mu = sum * (1.f / D_);
    float rstd = rsqrtf(sq * (1.f / D_) - mu * mu + 1e-5f);
    #pragma unroll
    for (int j = 0; j < 3; j++) {
        int d = tid + 256 * j;
        h[(size_t)row * D_ + d] = (v[j] - mu) * rstd * ln_w[d] + ln_b[d];
    }
}

__global__ __launch_bounds__(256) void rmsnorm_bf_kernel(const float* __restrict__ h,
                                                         const float* __restrict__ w,
                                                         bf16* __restrict__ out) {
    int row = blockIdx.x, tid = threadIdx.x;
    __shared__ float sbuf[8];
    float v[3], ss = 0.f, dummy = 0.f;
    #pragma unroll
    for (int j = 0; j < 3; j++) {
        v[j] = h[(size_t)row * D_ + tid + 256 * j];
        ss += v[j] * v[j];
    }
    block_reduce2_(ss, dummy, sbuf);
    float rstd = rsqrtf(ss * (1.f / D_) + 1e-5f);
    #pragma unroll
    for (int j = 0; j < 3; j++) {
        int d = tid + 256 * j;
        out[(size_t)row * D_ + d] = (bf16)(v[j] * rstd * w[d]);
    }
}

// conv K=4 + silu -> xc (4 channels/thread) ; gate u32 per (row,d) -> gag
__global__ __launch_bounds__(256) void conv_silu_kernel(const bf16* __restrict__ xzb,
                                                        const float* __restrict__ cw,
                                                        const float* __restrict__ cb,
                                                        const float* __restrict__ Dp,
                                                        bf16* __restrict__ xcb,
                                                        unsigned* __restrict__ gag) {
    size_t idx = (size_t)blockIdx.x * 256 + threadIdx.x;   // crows*DI_/4
    int d4 = (int)(idx % (DI_ / 4));
    size_t row = idx / (DI_ / 4);
    int t = (int)(row % L_);
    int d = d4 * 4;
    const uint2* xz64 = (const uint2*)xzb;                 // row stride 768 uint2
    size_t base = row * 768 + d4;
    uint2 z2{0u, 0u};
    uint2 p0  = xz64[base];
    uint2 pm1 = (t >= 1) ? xz64[base - 768]     : z2;
    uint2 pm2 = (t >= 2) ? xz64[base - 2 * 768] : z2;
    uint2 pm3 = (t >= 3) ? xz64[base - 3 * 768] : z2;
    uint2 pz  = xz64[base + 384];

    bf16x4 a0 = __builtin_bit_cast(bf16x4, p0);
    bf16x4 a1 = __builtin_bit_cast(bf16x4, pm1);
    bf16x4 a2 = __builtin_bit_cast(bf16x4, pm2);
    bf16x4 a3 = __builtin_bit_cast(bf16x4, pm3);
    bf16x4 az = __builtin_bit_cast(bf16x4, pz);

    float cbl[4], Dl[4];
    *(float4*)cbl = ((const float4*)cb)[d4];
    *(float4*)Dl  = ((const float4*)Dp)[d4];

    float u[4];
    unsigned gv[4];
    #pragma unroll
    for (int c = 0; c < 4; c++) {
        float4 wc = ((const float4*)cw)[d + c];
        float acc = cbl[c] + wc.x * (float)a3[c] + wc.y * (float)a2[c]
                           + wc.z * (float)a1[c] + wc.w * (float)a0[c];
        u[c] = silu_(acc);
        float gz = silu_((float)az[c]);
        gv[c] = pack_bf2_(Dl[c] * u[c] * gz, gz);
    }
    ((uint2*)xcb)[row * (DI_ / 4) + d4] = uint2{pack_bf2_(u[0], u[1]), pack_bf2_(u[2], u[3])};
    *(uint4*)(gag + row * DI_ + d) = uint4{gv[0], gv[1], gv[2], gv[3]};
}

// ============== single-pass scan v2.1: single-buffered lsw2/logds (occupancy) ==============
__global__ __launch_bounds__(256) void scan_lds_kernel(const float* __restrict__ bcf,
                                                       const unsigned* __restrict__ swg,
                                                       const unsigned* __restrict__ gag,
                                                       const float* __restrict__ A_log,
                                                       bf16* __restrict__ yb) {
    __shared__ float2   lsw2[16][TPW_];
    __shared__ char     lbcf[2][8192];
    __shared__ unsigned logds[16][TPO_];
    const int tid = threadIdx.x;
    const int n = tid & 15, dl = tid >> 4;
    const int d0 = blockIdx.x * 16;
    const int d = d0 + dl;
    const int b = blockIdx.y;
    const float AvL = -__expf(A_log[(size_t)d * N_ + n]) * 1.44269504f;
    const size_t seqbase = (size_t)b * L_;

    const char* bcf_base = (const char*)bcf + (size_t)b * NCHT_ * 8192;
    unsigned swr[4], gar[4];

    #define BCF_GLD(c) { const char* s_ = bcf_base + (size_t)(c) * 8192 + tid * 16;  \
        char* d_ = (char*)lbcf + ((c) & 1) * 8192 + tid * 16;                        \
        gld16(s_, d_); gld16(s_ + 4096, d_ + 4096); }
    #define REG_LOAD(c) { size_t rb = seqbase + (size_t)(c) * TCH_;                  \
        _Pragma("unroll") for (int i = 0; i < 4; i++) {                              \
            size_t g = (rb + dl + 16 * i) * DI_ + d0 + n;                            \
            swr[i] = swg[g]; gar[i] = gag[g]; } }
    #define DSWRITE() { _Pragma("unroll") for (int i = 0; i < 4; i++) {              \
            int t = dl + 16 * i;                                                     \
            bf16x2 w2 = __builtin_bit_cast(bf16x2, swr[i]);                          \
            lsw2[n][t] = float2{(float)w2.x, (float)w2.y};                           \
            logds[n][t] = gar[i]; } }

    BCF_GLD(0);
    REG_LOAD(0);
    DSWRITE();
    __syncthreads();
    REG_LOAD(1);

    float h = 0.f;
    for (int c = 0; c < NCHT_; c++) {
        if (c + 1 < NCHT_) BCF_GLD(c + 1);
        bf16* pyc = yb + (seqbase + (size_t)c * TCH_) * DI_ + d;
        const char* bcrow = (const char*)lbcf + (c & 1) * 8192;
        #pragma unroll
        for (int tb = 0; tb < TCH_; tb += 16) {
            float res = 0.f;
            #pragma unroll
            for (int tq = 0; tq < 16; tq += 2) {
                float4 dd = *(const float4*)&lsw2[dl][tb + tq];
                int byo = (n * 512 + (tb + tq) * 8) ^ ((n & 7) << 4);
                float4 bc = *(const float4*)(bcrow + byo);
                #pragma unroll
                for (int u = 0; u < 2; u++) {
                    float du  = u ? dd.z : dd.x;
                    float dtv = u ? dd.w : dd.y;
                    float Bv  = u ? bc.z : bc.x;
                    float Cv  = u ? bc.w : bc.y;
                    float dA = __builtin_amdgcn_exp2f(dtv * AvL);
                    h = dA * h + du * Bv;
                    float pq = h * Cv;
                    pq = dpp_add_<0xB1>(pq);
                    pq = dpp_add_<0x4E>(pq);
                    pq = dpp_add_<0x124>(pq);
                    pq = dpp_add_<0x128>(pq);
                    if (n == tq + u) res = pq;   // loop-invariant cmp -> hoisted mask
                }
            }
            unsigned og = logds[dl][tb + n];
            bf16x2 o2 = __builtin_bit_cast(bf16x2, og);
            pyc[(size_t)(tb + n) * DI_] = (bf16)(res * (float)o2.y + (float)o2.x);
        }
        if (c + 1 < NCHT_) {
            __syncthreads();             // all reads of chunk c done
            DSWRITE();                   // overwrite single-buffer streams with c+1
            __syncthreads();             // writes visible (also drains BCF_GLD vmcnt)
            if (c + 2 < NCHT_) REG_LOAD(c + 2);
        }
    }
    #undef BCF_GLD
    #undef REG_LOAD
    #undef DSWRITE
}

extern "C" void kernel_launch(void* const* d_in, const int* in_sizes, int n_in,
                              void* d_out, int out_size, void* d_ws, size_t ws_size,
                              hipStream_t stream) {
    const float* x        = (const float*)d_in[0];
    const float* stat     = (const float*)d_in[1];
    const int*   mask     = (const int*)d_in[3];
    const float* emb_w    = (const float*)d_in[5];
    const float* emb_b    = (const float*)d_in[6];
    const float* static_w = (const float*)d_in[7];
    const float* static_b = (const float*)d_in[8];
    const float* ln_w     = (const float*)d_in[9];
    const float* ln_b     = (const float*)d_in[10];
    const float* norm_w   = (const float*)d_in[11];
    const float* in_proj_w  = (const float*)d_in[12];
    const float* conv_w   = (const float*)d_in[13];
    const float* conv_b   = (const float*)d_in[14];
    const float* x_proj_w = (const float*)d_in[15];
    const float* dt_proj_w= (const float*)d_in[16];
    const float* dt_proj_b= (const float*)d_in[17];
    const float* A_log    = (const float*)d_in[18];
    const float* D_param  = (const float*)d_in[19];
    const float* out_proj_w = (const float*)d_in[20];
    const float* norm_f_w = (const float*)d_in[21];
    const float* lm_head_w= (const float*)d_in[22];
    float* out = (float*)d_out;

    // ---- batch chunking (CB=8; ws < 318 MiB rules out larger tiers -- measured R4/R6) ----
    const int CBr = 8;
    const int CROWSr = CBr * L_;
    const int NCHr = B_ / CBr;

    // tiers (cumulative): deepks at 224 MiB (+6.3e6), precast at 246 MiB (+21.2e6)
    // (pairproj removed: makespan analysis + R15 measurement show it is neutral)
    const bool deepks  = (ws_size >= (size_t)224 * 1024 * 1024);
    const bool precast = (ws_size >= (size_t)246 * 1024 * 1024);
    const int KSr  = deepks ? 8 : 4;
    const int KSLr = DI_ / KSr;
    const int NLW  = precast ? NL_ : 1;

    // ---- workspace layout (bytes) ----
    char* p = (char*)d_ws;
    float*    h      = (float*)p;         p += (size_t)ROWS_ * D_ * 4;           // 50.3 MB
    bf16*     hn_bf  = (bf16*)p;          p += (size_t)CROWSr * D_ * 2;
    char*     xz_region = p;                                                     // h_pre alias start
    bf16*     xz_bf  = (bf16*)p;          p += (size_t)CROWSr * 2 * DI_ * 2;
    bf16*     xc_bf  = (bf16*)p;          p += (size_t)CROWSr * DI_ * 2;
    unsigned* sw_g   = (unsigned*)p;      p += (size_t)CROWSr * DI_ * 4;
    unsigned* gate_g = (unsigned*)p;      p += (size_t)CROWSr * DI_ * 4;
    float*    bcf    = (float*)p;         p += (size_t)CROWSr * 32 * 4;
    bf16*     dtr_bf = (bf16*)p;          p += (size_t)CROWSr * 64 * 2;
    float*    pbuf   = (float*)p;         p += (size_t)KSr * CROWSr * 96 * 4;
    bf16*     y_bf   = (bf16*)p;          p += (size_t)ROWS_ * DI_ * 2;          // 50.3 (FULL batch)
    bf16*     inw_w  = (bf16*)p;          p += (size_t)NLW * 2 * DI_ * D_ * 2;
    bf16*     outw_w = (bf16*)p;          p += (size_t)NLW * D_ * DI_ * 2;
    bf16*     xpwp_bf= (bf16*)p;          p += (size_t)NL_ * 128 * DI_ * 2;      // 1.6
    bf16*     dtwp_bf= (bf16*)p;          p += (size_t)NL_ * DI_ * 64 * 2;       // 0.8
    bf16*     lmw_bf = (bf16*)p;          p += (size_t)128 * D_ * 2;
    bf16*     embw_bf= (bf16*)p;          p += (size_t)D_ * KE_ * 2;
    bf16*     feats  = (bf16*)p;          p += (size_t)ROWS_ * KE_ * 2;          // 3.1
    float*    sstat  = (float*)p;         p += (size_t)B_ * D_ * 4;
    float*    h_pre  = (float*)xz_region; // 50.3 MB alias over xz/xc/sw_g (dead then)
    bf16*     hn_full= (bf16*)sw_g;       // 25.2 MB alias (sw_g dead at final stage)

    // ---- weight prep ----
    pad_lm_kernel<<<(128 * D_) / 256, 256, 0, stream>>>(lm_head_w, lmw_bf);
    pad_embw_kernel<<<(D_ * KE_) / 256, 256, 0, stream>>>(emb_w, embw_bf);
    feats_kernel<<<(ROWS_ * KE_) / 256, 256, 0, stream>>>(x, mask, feats);
    dim3 gxp((128 * DI_) / 256, NL_);
    xpw_pad_kernel<<<gxp, 256, 0, stream>>>(x_proj_w, xpwp_bf);
    dim3 gdt((DI_ * 64) / 256, NL_);
    dtw_pad_kernel<<<gdt, 256, 0, stream>>>(dt_proj_w, dtwp_bf);
    sstat_kernel<<<(B_ * D_) / 256, 256, 0, stream>>>(stat, static_w, static_b, emb_b, sstat);
    if (precast) {
        const unsigned nin = (unsigned)(NL_ * 2 * DI_ * D_);
        const unsigned ntot = nin + (unsigned)(NL_ * D_ * DI_);
        cast2_f2b_kernel<<<ntot / 256, 256, 0, stream>>>(
            in_proj_w, inw_w, out_proj_w, outw_w, nin);
    }

    // ---- embed + LN ----
    gemm_mfma<0><<<(D_ / 128) * (ROWS_ / 128), 256, 0, stream>>>(
        feats, embw_bf, nullptr, h_pre, D_, KE_, D_ / 128,
        nullptr, nullptr, nullptr, nullptr);
    ln_embed_kernel<<<ROWS_, 256, 0, stream>>>(h_pre, sstat, ln_w, ln_b, h);

    // ---- layers ----
    for (int l = 0; l < NL_; l++) {
        const bf16* inw_l;
        const bf16* outw_l;
        if (precast) {
            inw_l  = inw_w  + (size_t)l * 2 * DI_ * D_;
            outw_l = outw_w + (size_t)l * D_ * DI_;
        } else {
            const unsigned nin = (unsigned)(2 * DI_ * D_);
            const unsigned ntot = nin + (unsigned)(D_ * DI_);
            cast2_f2b_kernel<<<ntot / 256, 256, 0, stream>>>(
                in_proj_w + (size_t)l * 2 * DI_ * D_, inw_w,
                out_proj_w + (size_t)l * D_ * DI_, outw_w, nin);
            inw_l = inw_w; outw_l = outw_w;
        }

        for (int c = 0; c < NCHr; c++) {
            float* hc = h + (size_t)c * CROWSr * D_;

            rmsnorm_bf_kernel<<<CROWSr, 256, 0, stream>>>(hc, norm_w + (size_t)l * D_, hn_bf);

            // 256x256 8-phase GEMM: M=CROWSr, N=3072, K=768
            gemm256<1><<<(CROWSr / 256) * (2 * DI_ / 256), 512, 0, stream>>>(
                hn_bf, inw_l, nullptr, xz_bf, 2 * DI_, D_, 2 * DI_ / 256);

            conv_silu_kernel<<<(CROWSr * (DI_ / 4)) / 256, 256, 0, stream>>>(
                xz_bf, conv_w + (size_t)l * DI_ * 4, conv_b + (size_t)l * DI_,
                D_param + (size_t)l * DI_, xc_bf, gate_g);

            dim3 g2a(KSr, CROWSr / 128);
            gemm_mfma<4><<<g2a, 256, 0, stream>>>(xc_bf, xpwp_bf + (size_t)l * 128 * DI_,
                                                  nullptr, nullptr, CROWSr, DI_, KSLr,
                                                  nullptr, nullptr, pbuf, nullptr);
            xpost_kernel<<<(CROWSr * 96) / 256, 256, 0, stream>>>(pbuf, dtr_bf, bcf,
                                                                  CROWSr, KSr);

            gemm_mfma<2><<<(DI_ / 128) * (CROWSr / 128), 256, 0, stream>>>(
                dtr_bf, dtwp_bf + (size_t)l * DI_ * 64, nullptr, nullptr, 0, 64, DI_ / 128,
                dt_proj_b + (size_t)l * DI_, sw_g, nullptr, xc_bf);

            dim3 gs(DI_ / 16, CBr);
            scan_lds_kernel<<<gs, 256, 0, stream>>>(bcf, sw_g, gate_g,
                                                    A_log + (size_t)l * DI_ * N_,
                                                    y_bf + (size_t)c * CROWSr * DI_);
        }

        // 256x256 8-phase GEMM: M=16384, N=768, K=1536 -> 192 blocks, residual add
        gemm256<0><<<(ROWS_ / 256) * (D_ / 256), 512, 0, stream>>>(
            y_bf, outw_l, h, h, D_, DI_, D_ / 256);
    }

    // ---- final rmsnorm + lm_head (full batch) ----
    rmsnorm_bf_kernel<<<ROWS_, 256, 0, stream>>>(h, norm_f_w, hn_full);
    gemm_mfma<0><<<ROWS_ / 128, 256, 0, stream>>>(
        hn_full, lmw_bf, nullptr, out, V_, D_, 1,
        nullptr, nullptr, nullptr, nullptr);
}